// Round 3
// baseline (199.043 us; speedup 1.0000x reference)
//
#include <hip/hip_runtime.h>
#include <hip/hip_bf16.h>
#include <stdint.h>

#define NB 8
#define LL 4096
#define LQ 2048
#define DD 128

typedef __attribute__((ext_vector_type(8))) short short8;   // bf16x8 MFMA frag
typedef __attribute__((ext_vector_type(4))) short short4v;  // bf16x4
typedef __attribute__((ext_vector_type(4))) float f4;
typedef __attribute__((ext_vector_type(2))) unsigned int u2;

__device__ __forceinline__ short8 pack8(const float* v) {
    __hip_bfloat16 h[8];
    #pragma unroll
    for (int j = 0; j < 8; ++j) h[j] = __float2bfloat16(v[j]);
    return *(short8*)h;
}

// ---------------------------------------------------------------------------
// Kernel A (MFMA): proj = x@W^T + b, q = avgpool2(x)@W^T + b
//   (unchanged from R1 — measured ~8 us, at its HBM write floor)
// ---------------------------------------------------------------------------
__global__ __launch_bounds__(256) void projA_kernel(
    const float* __restrict__ x, const float* __restrict__ W,
    const float* __restrict__ bias,
    __hip_bfloat16* __restrict__ proj, __hip_bfloat16* __restrict__ projT,
    __hip_bfloat16* __restrict__ qb, float* __restrict__ qf,
    float* __restrict__ psq, float* __restrict__ qsq)
{
    __shared__ __hip_bfloat16 Wlds[128 * 128];      // 32 KB, XOR-swizzled
    __shared__ __hip_bfloat16 Tt[4][128 * 16];      // 4 KB per-wave transpose tile

    const int tid = threadIdx.x;
    const int lane = tid & 63, w = tid >> 6;
    const int lr = lane & 15, lh = lane >> 4;       // frag row / k-chunk

    // ---- stage W -> bf16 swizzled LDS (fully coalesced f32 reads) ----
    #pragma unroll
    for (int k = 0; k < 16; ++k) {
        const int f = k * 1024 + tid * 4;           // flat f32 index
        const int e = f >> 7, col = f & 127;
        f4 v = *(const f4*)&W[f];
        __hip_bfloat16 h[4];
        #pragma unroll
        for (int j = 0; j < 4; ++j) h[j] = __float2bfloat16(v[j]);
        const int byte = e * 256 + (((col * 2)) ^ ((e & 7) << 4));
        *(u2*)((char*)Wlds + byte) = *(u2*)h;
    }
    float bv[8];
    #pragma unroll
    for (int nt = 0; nt < 8; ++nt) bv[nt] = bias[nt * 16 + lr];
    __syncthreads();

    const int tile = blockIdx.x;                    // 768 blocks, 1 tile each
    const int row0 = tile * 64 + w * 16;            // wave's 16 rows
    const bool qmode = tile >= (NB * LL / 64);      // >= 512

    short8 a[4];
    if (!qmode) {
        const float* src = x + (size_t)(row0 + lr) * DD;
        #pragma unroll
        for (int ks = 0; ks < 4; ++ks) {
            float t[8];
            *(f4*)&t[0] = *(const f4*)&src[ks * 32 + lh * 8];
            *(f4*)&t[4] = *(const f4*)&src[ks * 32 + lh * 8 + 4];
            a[ks] = pack8(t);
        }
    } else {
        const int gq = row0 - NB * LL + lr;         // global q row
        const int b = gq >> 11, l = gq & 2047;
        const float* s0 = x + ((size_t)b * LL + 2 * l) * DD;
        #pragma unroll
        for (int ks = 0; ks < 4; ++ks) {
            float t[8];
            f4 u0 = *(const f4*)&s0[ks * 32 + lh * 8];
            f4 u1 = *(const f4*)&s0[ks * 32 + lh * 8 + 4];
            f4 v0 = *(const f4*)&s0[DD + ks * 32 + lh * 8];
            f4 v1 = *(const f4*)&s0[DD + ks * 32 + lh * 8 + 4];
            *(f4*)&t[0] = (u0 + v0) * 0.5f;
            *(f4*)&t[4] = (u1 + v1) * 0.5f;
            a[ks] = pack8(t);
        }
    }

    f4 acc[8] = {};
    #pragma unroll
    for (int nt = 0; nt < 8; ++nt) {
        const int e = nt * 16 + lr;
        #pragma unroll
        for (int ks = 0; ks < 4; ++ks) {
            const int byte = e * 256 + ((ks * 64 + lh * 16) ^ ((lr & 7) << 4));
            short8 bk = *(const short8*)((char*)Wlds + byte);
            acc[nt] = __builtin_amdgcn_mfma_f32_16x16x32_bf16(a[ks], bk, acc[nt], 0, 0, 0);
        }
    }

    __hip_bfloat16 h[8][4];
    f4 rn = {0.f, 0.f, 0.f, 0.f};
    #pragma unroll
    for (int nt = 0; nt < 8; ++nt)
        #pragma unroll
        for (int r = 0; r < 4; ++r) {
            float v = acc[nt][r] + bv[nt];
            acc[nt][r] = v;
            h[nt][r] = __float2bfloat16(v);
            float vb = __bfloat162float(h[nt][r]);
            rn[r] += vb * vb;
        }
    #pragma unroll
    for (int m = 1; m < 16; m <<= 1) {
        #pragma unroll
        for (int r = 0; r < 4; ++r) rn[r] += __shfl_xor(rn[r], m);
    }

    if (!qmode) {
        const int gr = row0;
        #pragma unroll
        for (int nt = 0; nt < 8; ++nt)
            #pragma unroll
            for (int r = 0; r < 4; ++r)
                proj[(size_t)(gr + lh * 4 + r) * DD + nt * 16 + lr] = h[nt][r];
        if (lr == 0) *(f4*)&psq[gr + lh * 4] = rn;
        #pragma unroll
        for (int nt = 0; nt < 8; ++nt) {
            __hip_bfloat16 p[4] = {h[nt][0], h[nt][1], h[nt][2], h[nt][3]};
            *(u2*)((char*)&Tt[w][0] + (nt * 16 + lr) * 32 + lh * 8) = *(u2*)p;
        }
        const int b = gr >> 12, l0 = gr & 4095;
        #pragma unroll
        for (int i = 0; i < 2; ++i) {
            const int e = lane + i * 64;
            short8 t0 = *(const short8*)&Tt[w][e * 16];
            short8 t1 = *(const short8*)&Tt[w][e * 16 + 8];
            __hip_bfloat16* dst = projT + ((size_t)(b * DD + e)) * LL + l0;
            *(short8*)dst = t0;
            *(short8*)(dst + 8) = t1;
        }
    } else {
        const int gq = row0 - NB * LL;
        #pragma unroll
        for (int nt = 0; nt < 8; ++nt)
            #pragma unroll
            for (int r = 0; r < 4; ++r) {
                const size_t idx = (size_t)(gq + lh * 4 + r) * DD + nt * 16 + lr;
                qb[idx] = h[nt][r];
                qf[idx] = acc[nt][r];
            }
        if (lr == 0) *(f4*)&qsq[gq + lh * 4] = rn;
    }
}

// ---------------------------------------------------------------------------
// Kernel B: barrier-free fused similarity.
//   Swapped GEMM1: S^T = mfma(A=proj_keys, B=q) so each lane's sim values
//   land directly in GEMM2's A-fragment position (q = lane&15). Key dim is
//   the contract dim -> lane-local key permutation {4lh+j, 16+4lh+j} is
//   applied identically to projT's B-fragment reads (two 8B loads).
//   Each wave owns a 1024-key quarter; partial O summed across 4 waves
//   once at the end (single __syncthreads in the kernel).
// ---------------------------------------------------------------------------
__global__ __launch_bounds__(256, 2) void fused_kernel(
    const __hip_bfloat16* __restrict__ proj, const __hip_bfloat16* __restrict__ projT,
    const __hip_bfloat16* __restrict__ qb, const float* __restrict__ psq,
    const float* __restrict__ qsq, float* __restrict__ outk, float* __restrict__ outv)
{
    __shared__ float red[4][32][132];   // per-wave partial O, 67.6 KB

    const int bid = blockIdx.x;
    const int b = bid & 7;              // XCD-pinned batch
    const int qrow0 = (bid >> 3) * 32;
    const int tid = threadIdx.x;
    const int w = tid >> 6;
    const int lane = tid & 63;
    const int lr = lane & 15, lh = lane >> 4;

    const __hip_bfloat16* pjb = proj + (size_t)b * LL * DD;
    const __hip_bfloat16* ptb = projT + (size_t)b * DD * LL;
    const float* psb = psq + b * LL;

    // q fragments (GEMM1 B-operand): lane holds q[qt*16+lr][ks*32+lh*8 ..+7]
    short8 aq[2][4];
    const __hip_bfloat16* qbase = qb + ((size_t)b * LQ + qrow0) * DD;
    #pragma unroll
    for (int qt = 0; qt < 2; ++qt)
        #pragma unroll
        for (int ks = 0; ks < 4; ++ks)
            aq[qt][ks] = *(const short8*)&qbase[(size_t)(qt * 16 + lr) * DD + ks * 32 + lh * 8];
    float qn[2] = { qsq[b * LQ + qrow0 + lr], qsq[b * LQ + qrow0 + 16 + lr] };

    f4 oc[2][8] = {};                   // [qt][dt] partial O accumulators

    const int kbase = w * (LL / 4);     // wave's private 1024-key quarter
    for (int it = 0; it < (LL / 4) / 32; ++it) {
        const int kk = kbase + it * 32;

        // ---- GEMM1 (swapped): S^T[key][q], keys kk..kk+31 ----
        f4 s[2][2] = {};                // [kt][qt]
        #pragma unroll
        for (int ks = 0; ks < 4; ++ks) {
            short8 ak0 = *(const short8*)&pjb[(size_t)(kk + lr) * DD + ks * 32 + lh * 8];
            short8 ak1 = *(const short8*)&pjb[(size_t)(kk + 16 + lr) * DD + ks * 32 + lh * 8];
            s[0][0] = __builtin_amdgcn_mfma_f32_16x16x32_bf16(ak0, aq[0][ks], s[0][0], 0, 0, 0);
            s[0][1] = __builtin_amdgcn_mfma_f32_16x16x32_bf16(ak0, aq[1][ks], s[0][1], 0, 0, 0);
            s[1][0] = __builtin_amdgcn_mfma_f32_16x16x32_bf16(ak1, aq[0][ks], s[1][0], 0, 0, 0);
            s[1][1] = __builtin_amdgcn_mfma_f32_16x16x32_bf16(ak1, aq[1][ks], s[1][1], 0, 0, 0);
        }

        // ---- transform in-register: lane holds S^T[16kt+4lh+r][16qt+lr] ----
        f4 pn0 = *(const f4*)&psb[kk + lh * 4];
        f4 pn1 = *(const f4*)&psb[kk + 16 + lh * 4];
        short8 pa[2];
        #pragma unroll
        for (int qt = 0; qt < 2; ++qt) {
            __hip_bfloat16 hh[8];
            #pragma unroll
            for (int r = 0; r < 4; ++r) {
                float p0 = fmaxf(qn[qt] + pn0[r] - 2.0f * s[0][qt][r], 0.0f);
                float p1 = fmaxf(qn[qt] + pn1[r] - 2.0f * s[1][qt][r], 0.0f);
                hh[r]     = __float2bfloat16(__expf(-sqrtf(p0)));
                hh[4 + r] = __float2bfloat16(__expf(-sqrtf(p1)));
            }
            pa[qt] = *(short8*)hh;
        }

        // ---- GEMM2: O += sim @ proj, B from projT at the same key perm ----
        #pragma unroll
        for (int dt = 0; dt < 8; ++dt) {
            const __hip_bfloat16* rowp = ptb + (size_t)(dt * 16 + lr) * LL + kk;
            union { short8 v; short4v h[2]; } u;
            u.h[0] = *(const short4v*)&rowp[lh * 4];        // keys 4lh..4lh+3
            u.h[1] = *(const short4v*)&rowp[16 + lh * 4];   // keys 16+4lh..+3
            oc[0][dt] = __builtin_amdgcn_mfma_f32_16x16x32_bf16(pa[0], u.v, oc[0][dt], 0, 0, 0);
            oc[1][dt] = __builtin_amdgcn_mfma_f32_16x16x32_bf16(pa[1], u.v, oc[1][dt], 0, 0, 0);
        }
    }

    // ---- epilogue: sum the 4 wave-partials through LDS (one barrier) ----
    // C layout of GEMM2: O[q = qt*16 + lh*4 + r][d = dt*16 + lr]
    #pragma unroll
    for (int qt = 0; qt < 2; ++qt)
        #pragma unroll
        for (int dt = 0; dt < 8; ++dt)
            #pragma unroll
            for (int r = 0; r < 4; ++r)
                red[w][qt * 16 + lh * 4 + r][dt * 16 + lr] = oc[qt][dt][r];
    __syncthreads();

    const int row = tid >> 3;
    const int c0 = (tid & 7) * 16;
    float* dk = outk + ((size_t)b * LQ + qrow0 + row) * DD + c0;
    float* dv = outv + ((size_t)b * LQ + qrow0 + row) * DD + c0;
    #pragma unroll
    for (int i = 0; i < 4; ++i) {
        f4 v0 = *(const f4*)&red[0][row][c0 + i * 4];
        f4 v1 = *(const f4*)&red[1][row][c0 + i * 4];
        f4 v2 = *(const f4*)&red[2][row][c0 + i * 4];
        f4 v3 = *(const f4*)&red[3][row][c0 + i * 4];
        f4 vs = (v0 + v1) + (v2 + v3);
        *(f4*)&dk[i * 4] = vs;
        *(f4*)&dv[i * 4] = vs;
    }
}

extern "C" void kernel_launch(void* const* d_in, const int* in_sizes, int n_in,
                              void* d_out, int out_size, void* d_ws, size_t ws_size,
                              hipStream_t stream) {
    const float* x = (const float*)d_in[0];
    const float* W = (const float*)d_in[1];
    const float* bias = (const float*)d_in[2];

    float* out = (float*)d_out;
    const size_t NQ = (size_t)NB * LQ * DD;
    float* qf = out;            // output 0: q
    float* outk = out + NQ;     // output 1: k
    float* outv = out + 2 * NQ; // output 2: v

    char* ws = (char*)d_ws;
    __hip_bfloat16* proj  = (__hip_bfloat16*)ws;                          // 8 MB
    __hip_bfloat16* projT = (__hip_bfloat16*)(ws + 8u * 1024 * 1024);     // 8 MB
    __hip_bfloat16* qb    = (__hip_bfloat16*)(ws + 16u * 1024 * 1024);    // 4 MB
    float* psq            = (float*)(ws + 20u * 1024 * 1024);             // 128 KB
    float* qsq            = (float*)(ws + 20u * 1024 * 1024 + 256u * 1024); // 64 KB

    hipLaunchKernelGGL(projA_kernel, dim3((NB * LL + NB * LQ) / 64), dim3(256), 0, stream,
                       x, W, bias, proj, projT, qb, qf, psq, qsq);
    hipLaunchKernelGGL(fused_kernel, dim3(NB * (LQ / 32)), dim3(256), 0, stream,
                       proj, projT, qb, psq, qsq, outk, outv);
}